// Round 6
// baseline (8870.017 us; speedup 1.0000x reference)
//
#include <hip/hip_runtime.h>
#include <cmath>

// T=512, B=32, D=1024, H=1024, 3H=3072
// d_out: outputs (512*32*1024) ++ outputs[-1] (32*1024) ++ h_last (32*1024)  fp32

typedef short s8v  __attribute__((ext_vector_type(8)));   // 8 x bf16 (raw bits)
typedef float f4v  __attribute__((ext_vector_type(4)));   // MFMA accumulator

#define NB 64       // blocks in the GRU grid
#define GUARD 16384 // bounded-spin: degrade to wrong-answer instead of hanging

__device__ __forceinline__ short f2bf(float f) {
    return __builtin_bit_cast(short, (__bf16)f);          // RNE convert
}
__device__ __forceinline__ float bf2f(short s) {
    return (float)__builtin_bit_cast(__bf16, s);
}

// ---------------------------------------------------------------------------
// Transpose W [1024][3072] fp32  ->  Wt [3072][1024] bf16.
// ---------------------------------------------------------------------------
__global__ __launch_bounds__(256) void k_transpose_bf16(
        const float* __restrict__ W, short* __restrict__ Wt) {
    __shared__ short Ls[32][72];
    int bk = blockIdx.x & 31;
    int bn = blockIdx.x >> 5;
    int k0 = bk * 32, n0 = bn * 64;
    int tid = threadIdx.x;
    {
        int r  = tid >> 3;
        int c0 = (tid & 7) * 8;
        const float* src = W + (size_t)(k0 + r) * 3072 + n0 + c0;
        float4 f0 = *reinterpret_cast<const float4*>(src);
        float4 f1 = *reinterpret_cast<const float4*>(src + 4);
        Ls[r][c0+0] = f2bf(f0.x); Ls[r][c0+1] = f2bf(f0.y);
        Ls[r][c0+2] = f2bf(f0.z); Ls[r][c0+3] = f2bf(f0.w);
        Ls[r][c0+4] = f2bf(f1.x); Ls[r][c0+5] = f2bf(f1.y);
        Ls[r][c0+6] = f2bf(f1.z); Ls[r][c0+7] = f2bf(f1.w);
    }
    __syncthreads();
    {
        int j   = tid >> 2;
        int kk0 = (tid & 3) * 8;
        s8v v;
        #pragma unroll
        for (int s = 0; s < 8; ++s) v[s] = Ls[kk0 + s][j];
        *reinterpret_cast<s8v*>(Wt + (size_t)(n0 + j) * 1024 + k0 + kk0) = v;
    }
}

// ---------------------------------------------------------------------------
// gi = X @ W_ih.  M=16384, N=3072, K=1024.  Output bf16.
// ---------------------------------------------------------------------------
__global__ __launch_bounds__(256) void k_gemm_gi(
        const float* __restrict__ X, const short* __restrict__ Wt,
        short* __restrict__ gi) {
    __shared__ short As[64][40];
    __shared__ short Bs[64][40];
    int bm = blockIdx.x & 255;
    int bn = blockIdx.x >> 8;
    int m0 = bm * 64, n0 = bn * 64;
    int tid = threadIdx.x;
    int wid = tid >> 6, l = tid & 63;
    int wm = wid >> 1, wn = wid & 1;
    int lr = l & 15, q = l >> 4;
    f4v acc[2][2] = {};
    int sr = tid >> 2;
    int sc = (tid & 3) * 8;

    for (int kc = 0; kc < 1024; kc += 32) {
        const float* asrc = X + (size_t)(m0 + sr) * 1024 + kc + sc;
        float4 f0 = *reinterpret_cast<const float4*>(asrc);
        float4 f1 = *reinterpret_cast<const float4*>(asrc + 4);
        s8v av;
        av[0]=f2bf(f0.x); av[1]=f2bf(f0.y); av[2]=f2bf(f0.z); av[3]=f2bf(f0.w);
        av[4]=f2bf(f1.x); av[5]=f2bf(f1.y); av[6]=f2bf(f1.z); av[7]=f2bf(f1.w);
        *reinterpret_cast<s8v*>(&As[sr][sc]) = av;
        *reinterpret_cast<s8v*>(&Bs[sr][sc]) =
            *reinterpret_cast<const s8v*>(Wt + (size_t)(n0 + sr) * 1024 + kc + sc);
        __syncthreads();
        s8v a0 = *reinterpret_cast<const s8v*>(&As[wm*32 +  0 + lr][q*8]);
        s8v a1 = *reinterpret_cast<const s8v*>(&As[wm*32 + 16 + lr][q*8]);
        s8v b0 = *reinterpret_cast<const s8v*>(&Bs[wn*32 +  0 + lr][q*8]);
        s8v b1 = *reinterpret_cast<const s8v*>(&Bs[wn*32 + 16 + lr][q*8]);
        acc[0][0] = __builtin_amdgcn_mfma_f32_16x16x32_bf16(a0, b0, acc[0][0], 0,0,0);
        acc[0][1] = __builtin_amdgcn_mfma_f32_16x16x32_bf16(a0, b1, acc[0][1], 0,0,0);
        acc[1][0] = __builtin_amdgcn_mfma_f32_16x16x32_bf16(a1, b0, acc[1][0], 0,0,0);
        acc[1][1] = __builtin_amdgcn_mfma_f32_16x16x32_bf16(a1, b1, acc[1][1], 0,0,0);
        __syncthreads();
    }
    #pragma unroll
    for (int ms = 0; ms < 2; ++ms)
      #pragma unroll
      for (int ns = 0; ns < 2; ++ns) {
        int m = m0 + wm*32 + ms*16 + q*4;
        int n = n0 + wn*32 + ns*16 + lr;
        #pragma unroll
        for (int i = 0; i < 4; ++i)
            gi[(size_t)(m + i) * 3072 + n] = f2bf(acc[ms][ns][i]);
      }
}

// ---------------------------------------------------------------------------
// GRU recurrence v9 — v8's proven tag protocol + 4-wave K-split consume.
//
// v8 (passed, exact) lost to round-0 because its consume was 4 control-
// dependent round-trips (batch bb+1's loads gated on batch bb's tag check).
// v9: 4 waves/block = (batch half w) x (K half kh). Each wave polls only its
// own 64 tagged u64 (128 VGPR -> fits one register sweep; launch_bounds
// (256,1) => 1 wave/SIMD => up to 256 arch VGPRs) in ONE non-serialized
// sweep: issue all 64 atomic loads, one wait, check all 64 tags, rare
// re-sweep. K-half partial accumulators reduce through LDS (2 barriers);
// kh=0 waves do gates/publish/out. K-half waves also wait on DISJOINT
// producer sets (blocks 0-31 vs 32-63) -> parallel detect.
//
// Protocol byte-for-byte v8: u64 quantum {2 x bf16 | tag}, 64-bit naturally
// aligned => single-copy atomic (no v6 tearing); gate-before-publish.
// The B1 barrier couples kh=1's consumption into the block's flag: flag=t+1
// implies BOTH K-half waves consumed t, so the overwrite-safety induction
// closes exactly as in v8. Bounded spins degrade bugs to fast wrong answers.
// ---------------------------------------------------------------------------
__global__ __launch_bounds__(256, 1) void k_gru(
        const float* __restrict__ pad,   // [512][32]
        const short* __restrict__ gi,    // [16384][3072] bf16 (no bias)
        const short* __restrict__ Whht,  // [3072][1024] bf16
        const float* __restrict__ b_ih,  // [3072]
        const float* __restrict__ b_hh,  // [3072]
        unsigned long long* __restrict__ hb3,  // [2][32][512] tagged u64 (zeroed)
        unsigned* __restrict__ flags,    // [2][64] step flags (pre-zeroed)
        float* __restrict__ out) {
    extern __shared__ short wlds[];      // 48 rows x 1024, stride 1032 shorts
    const int WS = 1032;
    float* rlds = (float*)((char*)wlds + 99072);   // [2][64][13] reduce slab
    int bid = blockIdx.x;                // 0..63
    int j0  = bid * 16;
    int tid = threadIdx.x;               // 0..255
    int ww  = tid >> 6;                  // wave id 0..3
    int w   = ww & 1;                    // batch half
    int kh  = ww >> 1;                   // K half
    int l   = tid & 63, lr = l & 15, q = l >> 4;

    // Stage weight slice: rows (gate g, col c) x 1024 shorts. (all 4 waves)
    for (int idx = tid; idx < 48 * 128; idx += 256) {
        int row = idx >> 7;
        int ko  = (idx & 127) * 8;
        int g = row >> 4, c = row & 15;
        *reinterpret_cast<s8v*>(&wlds[(g * 16 + c) * WS + ko]) =
            *reinterpret_cast<const s8v*>(Whht + (size_t)(g * 1024 + j0 + c) * 1024 + ko);
    }
    __syncthreads();                     // weights ready

    int jq = j0 + q * 4;                 // first of this lane's 4 j-cols
    int b  = w * 16 + lr;                // this lane's batch row
    // weight pointers include this wave's K-half offset
    const short* w_r = &wlds[(0 * 16 + lr) * WS + kh * 512 + q * 8];
    const short* w_z = &wlds[(1 * 16 + lr) * WS + kh * 512 + q * 8];
    const short* w_n = &wlds[(2 * 16 + lr) * WS + kh * 512 + q * 8];
    float* rslot = rlds + (size_t)(w * 64 + l) * 13;   // stride 13: 2-way banks

    // kh=0-only state
    f4v sbr = {0,0,0,0}, sbz = {0,0,0,0}, sbn_i = {0,0,0,0}, sbn_h = {0,0,0,0};
    float hp[4] = {0.f, 0.f, 0.f, 0.f};
    union u64s { unsigned long long u; short s[4]; };
    u64s gr_, gz_, gn_; float pv = 0.f;
    gr_.u = gz_.u = gn_.u = 0ull;
    const unsigned* myflags = flags + w * 64 + l;   // own-half flag of block l
    if (kh == 0) {
        sbr = *reinterpret_cast<const f4v*>(b_ih + jq)
            + *reinterpret_cast<const f4v*>(b_hh + jq);
        sbz = *reinterpret_cast<const f4v*>(b_ih + 1024 + jq)
            + *reinterpret_cast<const f4v*>(b_hh + 1024 + jq);
        sbn_i = *reinterpret_cast<const f4v*>(b_ih + 2048 + jq);
        sbn_h = *reinterpret_cast<const f4v*>(b_hh + 2048 + jq);
        const short* gp = gi + (size_t)b * 3072 + jq;    // prefetch t=0
        gr_.u = *reinterpret_cast<const unsigned long long*>(gp);
        gz_.u = *reinterpret_cast<const unsigned long long*>(gp + 1024);
        gn_.u = *reinterpret_cast<const unsigned long long*>(gp + 2048);
        pv = pad[b];
    }

    for (int t = 0; t < 512; ++t) {
        unsigned tg = (unsigned)t;
        // lane (b,q,kh) needs h[b][k], k = kh*512 + it*32 + q*8 .. +8,
        // it = 0..15  ->  u64 idx = kh*256 + it*16 + q*4 + j, j = 0..3.
        const unsigned long long* hrow =
            hb3 + (size_t)((t & 1) * 32 + b) * 512 + kh * 256 + q * 4;

        // ---- 1. single-sweep tagged consume (64 u64, one waitcnt) ----
        unsigned long long hv[64];
        int guard = 0;
        for (;;) {
            #pragma unroll
            for (int it = 0; it < 16; ++it)
                #pragma unroll
                for (int j = 0; j < 4; ++j)
                    hv[it*4 + j] = __hip_atomic_load(
                        hrow + it * 16 + j,
                        __ATOMIC_RELAXED, __HIP_MEMORY_SCOPE_AGENT);
            int ok = 1;
            #pragma unroll
            for (int k2 = 0; k2 < 64; ++k2)
                ok &= (int)((unsigned)hv[k2] == tg);
            if (__all(ok)) break;
            if (++guard > GUARD) break;      // anti-hang: degrade, don't die
            __builtin_amdgcn_s_sleep(1);
        }

        // ---- 2. flag prefetch (kh=0; used by the gate after reduce) ----
        unsigned flg = 0;
        if (kh == 0)
            flg = __hip_atomic_load(myflags, __ATOMIC_RELAXED,
                                    __HIP_MEMORY_SCOPE_AGENT);

        // ---- 3. MFMA over this wave's K half ----
        f4v ar = {0,0,0,0}, az = {0,0,0,0}, an = {0,0,0,0};
        #pragma unroll
        for (int it = 0; it < 16; ++it) {
            union { unsigned u[4]; s8v v; } hx;
            #pragma unroll
            for (int j = 0; j < 4; ++j)
                hx.u[j] = (unsigned)(hv[it*4 + j] >> 32);
            s8v r8 = *reinterpret_cast<const s8v*>(w_r + it * 32);
            s8v z8 = *reinterpret_cast<const s8v*>(w_z + it * 32);
            s8v n8 = *reinterpret_cast<const s8v*>(w_n + it * 32);
            ar = __builtin_amdgcn_mfma_f32_16x16x32_bf16(r8, hx.v, ar, 0,0,0);
            az = __builtin_amdgcn_mfma_f32_16x16x32_bf16(z8, hx.v, az, 0,0,0);
            an = __builtin_amdgcn_mfma_f32_16x16x32_bf16(n8, hx.v, an, 0,0,0);
        }

        // ---- 4. cross-K-half reduce through LDS ----
        if (kh == 1) {
            #pragma unroll
            for (int i = 0; i < 4; ++i) {
                rslot[i]     = ar[i];
                rslot[4 + i] = az[i];
                rslot[8 + i] = an[i];
            }
        }
        __syncthreads();                 // B1: partials visible
        if (kh == 0) {
            #pragma unroll
            for (int i = 0; i < 4; ++i) {
                ar[i] += rslot[i];
                az[i] += rslot[4 + i];
                an[i] += rslot[8 + i];
            }
        }
        __syncthreads();                 // B2: slab reusable next step

        if (kh == 0) {
            // ---- 5. gates ----
            #pragma unroll
            for (int i = 0; i < 4; ++i) {
                float xr = bf2f(gr_.s[i]) + ar[i] + sbr[i];
                float xz = bf2f(gz_.s[i]) + az[i] + sbz[i];
                float r  = __builtin_amdgcn_rcpf(1.f + __expf(-xr));
                float z  = __builtin_amdgcn_rcpf(1.f + __expf(-xz));
                float xn = bf2f(gn_.s[i]) + sbn_i[i] + r * (an[i] + sbn_h[i]);
                float e2 = __expf(2.f * xn);
                float n  = 1.f - 2.f * __builtin_amdgcn_rcpf(1.f + e2);  // tanh
                float hnv = (1.f - z) * n + z * hp[i];
                hnv = pv * hp[i] + (1.f - pv) * hnv;
                hp[i] = hnv;
            }

            // ---- 6. overwrite-safety gate (steady state: free) ----
            if (t && t < 511) {
                unsigned uT = (unsigned)t;
                int g2 = 0;
                while (!__all((int)(flg >= uT))) {
                    if (++g2 > GUARD) break;     // anti-hang
                    __builtin_amdgcn_s_sleep(1);
                    flg = __hip_atomic_load(myflags, __ATOMIC_RELAXED,
                                            __HIP_MEMORY_SCOPE_AGENT);
                }
            }

            int rowg = t * 32 + b;

            // ---- 7. publish: 2 tagged u64 stores + flag. NO waitcnt. ----
            if (t < 511) {
                unsigned long long tg1 = (unsigned long long)(t + 1);
                unsigned p01 = ((unsigned)(unsigned short)f2bf(hp[1]) << 16)
                             |  (unsigned)(unsigned short)f2bf(hp[0]);
                unsigned p23 = ((unsigned)(unsigned short)f2bf(hp[3]) << 16)
                             |  (unsigned)(unsigned short)f2bf(hp[2]);
                unsigned long long* hwr =
                    hb3 + (size_t)((((t + 1) & 1) * 32 + b)) * 512 + (jq >> 1);
                __hip_atomic_store(hwr,     ((unsigned long long)p01 << 32) | tg1,
                                   __ATOMIC_RELAXED, __HIP_MEMORY_SCOPE_AGENT);
                __hip_atomic_store(hwr + 1, ((unsigned long long)p23 << 32) | tg1,
                                   __ATOMIC_RELAXED, __HIP_MEMORY_SCOPE_AGENT);
                if (l == 0)
                    __hip_atomic_store(flags + w * 64 + bid, (unsigned)(t + 1),
                                       __ATOMIC_RELAXED, __HIP_MEMORY_SCOPE_AGENT);
            }

            // ---- 8. out stores + gi/pad prefetch, strictly after publish ----
            float4 o4 = { hp[0], hp[1], hp[2], hp[3] };
            *reinterpret_cast<float4*>(out + (size_t)rowg * 1024 + jq) = o4;
            if (t == 511) {
                *reinterpret_cast<float4*>(out + 16777216 + b * 1024 + jq) = o4;
                *reinterpret_cast<float4*>(out + 16809984 + b * 1024 + jq) = o4;
            }
            if (t < 511) {
                const short* gp = gi + (size_t)((t + 1) * 32 + b) * 3072 + jq;
                gr_.u = *reinterpret_cast<const unsigned long long*>(gp);
                gz_.u = *reinterpret_cast<const unsigned long long*>(gp + 1024);
                gn_.u = *reinterpret_cast<const unsigned long long*>(gp + 2048);
                pv = pad[(t + 1) * 32 + b];
            }
        }
    }
}

// ---------------------------------------------------------------------------
extern "C" void kernel_launch(void* const* d_in, const int* in_sizes, int n_in,
                              void* d_out, int out_size, void* d_ws, size_t ws_size,
                              hipStream_t stream) {
    const float* X   = (const float*)d_in[0];
    const float* pad = (const float*)d_in[1];
    const float* Wih = (const float*)d_in[2];
    const float* Whh = (const float*)d_in[3];
    const float* bih = (const float*)d_in[4];
    const float* bhh = (const float*)d_in[5];
    float* out = (float*)d_out;

    char* ws = (char*)d_ws;
    short*    gi    = (short*)(ws);                      // 100,663,296 B
    short*    Wih_t = (short*)(ws + 100663296);          //   6,291,456 B (dead after gemm)
    short*    Whh_t = (short*)(ws + 106954752);          //   6,291,456 B
    unsigned long long* hb3 =
        (unsigned long long*)(ws + 100663296);           // reuses Wih_t: 262,144 B
    unsigned* flags = (unsigned*)(ws + 100663296 + 262144);  // 512 B

    hipLaunchKernelGGL(k_transpose_bf16, dim3(1536), dim3(256), 0, stream, Wih, Wih_t);
    hipLaunchKernelGGL(k_transpose_bf16, dim3(1536), dim3(256), 0, stream, Whh, Whh_t);
    hipLaunchKernelGGL(k_gemm_gi, dim3(256 * 48), dim3(256), 0, stream, X, Wih_t, gi);

    // Zero the tagged-u64 buffer (h0 = 0, tags = 0 = valid step-0 state)
    // + flags. Enqueued AFTER the gemm so the Wih_t aliasing is stream-safe.
    hipMemsetAsync(hb3, 0, 262144 + 512, stream);

    // dynamic LDS: 99072 (weights) + 6656 (reduce slab) = 105728 B
    hipFuncSetAttribute((const void*)k_gru,
                        hipFuncAttributeMaxDynamicSharedMemorySize, 105728);
    hipLaunchKernelGGL(k_gru, dim3(NB), dim3(256), 105728, stream,
                       pad, gi, Whh_t, bih, bhh, hb3, flags, out);
}

// Round 7
// 4917.848 us; speedup vs baseline: 1.8036x; 1.8036x over previous
//
#include <hip/hip_runtime.h>
#include <cmath>

// T=512, B=32, D=1024, H=1024, 3H=3072
// d_out: outputs (512*32*1024) ++ outputs[-1] (32*1024) ++ h_last (32*1024)  fp32

typedef short s8v  __attribute__((ext_vector_type(8)));   // 8 x bf16 (raw bits)
typedef float f4v  __attribute__((ext_vector_type(4)));   // MFMA accumulator

#define NB 64       // blocks in the GRU grid
#define GUARD 16384 // bounded-spin: degrade to wrong-answer instead of hanging

__device__ __forceinline__ short f2bf(float f) {
    return __builtin_bit_cast(short, (__bf16)f);          // RNE convert
}
__device__ __forceinline__ float bf2f(short s) {
    return (float)__builtin_bit_cast(__bf16, s);
}

// ---------------------------------------------------------------------------
// Transpose W [1024][3072] fp32  ->  Wt [3072][1024] bf16.
// ---------------------------------------------------------------------------
__global__ __launch_bounds__(256) void k_transpose_bf16(
        const float* __restrict__ W, short* __restrict__ Wt) {
    __shared__ short Ls[32][72];
    int bk = blockIdx.x & 31;
    int bn = blockIdx.x >> 5;
    int k0 = bk * 32, n0 = bn * 64;
    int tid = threadIdx.x;
    {
        int r  = tid >> 3;
        int c0 = (tid & 7) * 8;
        const float* src = W + (size_t)(k0 + r) * 3072 + n0 + c0;
        float4 f0 = *reinterpret_cast<const float4*>(src);
        float4 f1 = *reinterpret_cast<const float4*>(src + 4);
        Ls[r][c0+0] = f2bf(f0.x); Ls[r][c0+1] = f2bf(f0.y);
        Ls[r][c0+2] = f2bf(f0.z); Ls[r][c0+3] = f2bf(f0.w);
        Ls[r][c0+4] = f2bf(f1.x); Ls[r][c0+5] = f2bf(f1.y);
        Ls[r][c0+6] = f2bf(f1.z); Ls[r][c0+7] = f2bf(f1.w);
    }
    __syncthreads();
    {
        int j   = tid >> 2;
        int kk0 = (tid & 3) * 8;
        s8v v;
        #pragma unroll
        for (int s = 0; s < 8; ++s) v[s] = Ls[kk0 + s][j];
        *reinterpret_cast<s8v*>(Wt + (size_t)(n0 + j) * 1024 + k0 + kk0) = v;
    }
}

// ---------------------------------------------------------------------------
// gi = X @ W_ih.  M=16384, N=3072, K=1024.  Output bf16.
// ---------------------------------------------------------------------------
__global__ __launch_bounds__(256) void k_gemm_gi(
        const float* __restrict__ X, const short* __restrict__ Wt,
        short* __restrict__ gi) {
    __shared__ short As[64][40];
    __shared__ short Bs[64][40];
    int bm = blockIdx.x & 255;
    int bn = blockIdx.x >> 8;
    int m0 = bm * 64, n0 = bn * 64;
    int tid = threadIdx.x;
    int wid = tid >> 6, l = tid & 63;
    int wm = wid >> 1, wn = wid & 1;
    int lr = l & 15, q = l >> 4;
    f4v acc[2][2] = {};
    int sr = tid >> 2;
    int sc = (tid & 3) * 8;

    for (int kc = 0; kc < 1024; kc += 32) {
        const float* asrc = X + (size_t)(m0 + sr) * 1024 + kc + sc;
        float4 f0 = *reinterpret_cast<const float4*>(asrc);
        float4 f1 = *reinterpret_cast<const float4*>(asrc + 4);
        s8v av;
        av[0]=f2bf(f0.x); av[1]=f2bf(f0.y); av[2]=f2bf(f0.z); av[3]=f2bf(f0.w);
        av[4]=f2bf(f1.x); av[5]=f2bf(f1.y); av[6]=f2bf(f1.z); av[7]=f2bf(f1.w);
        *reinterpret_cast<s8v*>(&As[sr][sc]) = av;
        *reinterpret_cast<s8v*>(&Bs[sr][sc]) =
            *reinterpret_cast<const s8v*>(Wt + (size_t)(n0 + sr) * 1024 + kc + sc);
        __syncthreads();
        s8v a0 = *reinterpret_cast<const s8v*>(&As[wm*32 +  0 + lr][q*8]);
        s8v a1 = *reinterpret_cast<const s8v*>(&As[wm*32 + 16 + lr][q*8]);
        s8v b0 = *reinterpret_cast<const s8v*>(&Bs[wn*32 +  0 + lr][q*8]);
        s8v b1 = *reinterpret_cast<const s8v*>(&Bs[wn*32 + 16 + lr][q*8]);
        acc[0][0] = __builtin_amdgcn_mfma_f32_16x16x32_bf16(a0, b0, acc[0][0], 0,0,0);
        acc[0][1] = __builtin_amdgcn_mfma_f32_16x16x32_bf16(a0, b1, acc[0][1], 0,0,0);
        acc[1][0] = __builtin_amdgcn_mfma_f32_16x16x32_bf16(a1, b0, acc[1][0], 0,0,0);
        acc[1][1] = __builtin_amdgcn_mfma_f32_16x16x32_bf16(a1, b1, acc[1][1], 0,0,0);
        __syncthreads();
    }
    #pragma unroll
    for (int ms = 0; ms < 2; ++ms)
      #pragma unroll
      for (int ns = 0; ns < 2; ++ns) {
        int m = m0 + wm*32 + ms*16 + q*4;
        int n = n0 + wn*32 + ns*16 + lr;
        #pragma unroll
        for (int i = 0; i < 4; ++i)
            gi[(size_t)(m + i) * 3072 + n] = f2bf(acc[ms][ns][i]);
      }
}

// ---------------------------------------------------------------------------
// GRU recurrence v10 — round-0 pipelined skeleton + in-consume tag validation.
//
// Lesson from v8/v9 counters: a tag CHECK placed between load and use forces
// the whole sweep array live at once -> spill (v9: VGPR 108 + scratch) or
// 4 control-dependent RTs (v8). Round-0 avoided both because its consume
// loop uses loads IN ORDER with no intervening check -> LLVM windows the
// loads into a single pipelined burst (one RT total).
// v10 keeps that structure and fuses validation INTO the consume loop
// (ok &= tag==t at unpack), wrapped in a redo loop. Same liveness as
// round-0; validation is free VALU under MFMA; stragglers cost a rare
// re-burst (data per tag is write-once -> monotone-stable validation).
//
// Protocol (components each proven in v8/v9 or round-0):
//   h quantum: u64 = {2 x bf16 (high dword) | step tag (low dword)} —
//     naturally-aligned 64-bit => single-copy atomic (no v6 tearing).
//   flags[64][2]: wave (bid,w) raises flags[bid*2+w]=t+1 IMMEDIATELY after
//     its 2 tagged u64 stores — NO waitcnt ACK (tags carry data validity).
//   The consumer's flag wait (all own-half flags >= t) doubles as the
//     overwrite-safety gate: flag[j] >= t  <=>  wave j consumed t-1, so
//     slots polled at step t can hold only tags {<=t}: a writer of t+2
//     (parity of t) needs all flags >= t+1, but a wave still validating t
//     has flag <= t. Compare==t is therefore exact. Deadlock-free by the
//     v8 induction. memset(0) = valid step-0 state (tag 0, h=0).
// Per-step serial chain: flag-visible -> detect -> 1 pipelined burst ->
// MFMA+gates -> publish (fire-and-forget). The round-0 ACK RT is gone.
// ---------------------------------------------------------------------------
__global__ __launch_bounds__(128, 1) void k_gru(
        const float* __restrict__ pad,   // [512][32]
        const short* __restrict__ gi,    // [16384][3072] bf16 (no bias)
        const short* __restrict__ Whht,  // [3072][1024] bf16
        const float* __restrict__ b_ih,  // [3072]
        const float* __restrict__ b_hh,  // [3072]
        unsigned long long* __restrict__ hb3,  // [2][32][512] tagged u64 (zeroed)
        unsigned* __restrict__ flags,    // [64][2] step flags (pre-zeroed)
        float* __restrict__ out) {
    extern __shared__ short wlds[];      // 48 rows x 1024, stride 1032 shorts
    const int WS = 1032;
    int bid = blockIdx.x;                // 0..63
    int j0  = bid * 16;
    int tid = threadIdx.x;               // 0..127
    int w   = tid >> 6;                  // batch half
    int l   = tid & 63, lr = l & 15, q = l >> 4;

    // Stage weight slice: rows (gate g, col c) x 1024 shorts. (both waves)
    for (int idx = tid; idx < 48 * 128; idx += 128) {
        int row = idx >> 7;
        int ko  = (idx & 127) * 8;
        int g = row >> 4, c = row & 15;
        *reinterpret_cast<s8v*>(&wlds[(g * 16 + c) * WS + ko]) =
            *reinterpret_cast<const s8v*>(Whht + (size_t)(g * 1024 + j0 + c) * 1024 + ko);
    }
    __syncthreads();                     // weights ready; last sync in kernel

    int jq = j0 + q * 4;                 // first of this lane's 4 j-cols
    int b  = w * 16 + lr;                // this lane's batch row
    f4v sbr = *reinterpret_cast<const f4v*>(b_ih + jq)
            + *reinterpret_cast<const f4v*>(b_hh + jq);
    f4v sbz = *reinterpret_cast<const f4v*>(b_ih + 1024 + jq)
            + *reinterpret_cast<const f4v*>(b_hh + 1024 + jq);
    f4v sbn_i = *reinterpret_cast<const f4v*>(b_ih + 2048 + jq);
    f4v sbn_h = *reinterpret_cast<const f4v*>(b_hh + 2048 + jq);
    const short* w_r = &wlds[(0 * 16 + lr) * WS + q * 8];
    const short* w_z = &wlds[(1 * 16 + lr) * WS + q * 8];
    const short* w_n = &wlds[(2 * 16 + lr) * WS + q * 8];
    float hp[4] = {0.f, 0.f, 0.f, 0.f};

    const unsigned* myflag = flags + l * 2 + w;   // own-half flag of block l

    union u64s { unsigned long long u; short s[4]; };
    u64s gr_, gz_, gn_; float pv;
    {   // prefetch gi/pad for t=0
        const short* gp = gi + (size_t)b * 3072 + jq;
        gr_.u = *reinterpret_cast<const unsigned long long*>(gp);
        gz_.u = *reinterpret_cast<const unsigned long long*>(gp + 1024);
        gn_.u = *reinterpret_cast<const unsigned long long*>(gp + 2048);
        pv = pad[b];
    }

    for (int t = 0; t < 512; ++t) {
        // ---- 1. flag wait: detect pre-filter AND overwrite-safety gate ----
        if (t) {
            unsigned uT = (unsigned)t;
            int g1 = 0;
            for (;;) {
                unsigned f = __hip_atomic_load(myflag, __ATOMIC_RELAXED,
                                               __HIP_MEMORY_SCOPE_AGENT);
                if (__all((int)(f >= uT))) break;
                if (++g1 > GUARD) break;     // anti-hang: degrade, don't die
                __builtin_amdgcn_s_sleep(1);
            }
        }

        // ---- 2. tagged burst; validate INSIDE the consume loop; redo ----
        // lane (b,q) needs h[b][k], k = it*32 + q*8 .. +8, it = 0..31
        //   -> u64 idx = it*16 + q*4 + j, j = 0..3.
        const unsigned long long* hrow =
            hb3 + (size_t)((t & 1) * 32 + b) * 512 + q * 4;
        unsigned tg = (unsigned)t;
        f4v ar, az, an;
        int g2 = 0;
        for (;;) {
            unsigned long long hreg[128];
            #pragma unroll
            for (int it = 0; it < 32; ++it)
                #pragma unroll
                for (int j = 0; j < 4; ++j)
                    hreg[it*4 + j] = __hip_atomic_load(hrow + it * 16 + j,
                        __ATOMIC_RELAXED, __HIP_MEMORY_SCOPE_AGENT);
            ar = (f4v){0,0,0,0}; az = (f4v){0,0,0,0}; an = (f4v){0,0,0,0};
            int ok = 1;
            #pragma unroll
            for (int it = 0; it < 32; ++it) {
                union { unsigned u[4]; s8v v; } hx;
                #pragma unroll
                for (int j = 0; j < 4; ++j) {
                    unsigned long long hv = hreg[it*4 + j];
                    ok &= (int)((unsigned)hv == tg);       // free under MFMA
                    hx.u[j] = (unsigned)(hv >> 32);
                }
                s8v r8 = *reinterpret_cast<const s8v*>(w_r + it * 32);
                s8v z8 = *reinterpret_cast<const s8v*>(w_z + it * 32);
                s8v n8 = *reinterpret_cast<const s8v*>(w_n + it * 32);
                ar = __builtin_amdgcn_mfma_f32_16x16x32_bf16(r8, hx.v, ar, 0,0,0);
                az = __builtin_amdgcn_mfma_f32_16x16x32_bf16(z8, hx.v, az, 0,0,0);
                an = __builtin_amdgcn_mfma_f32_16x16x32_bf16(n8, hx.v, an, 0,0,0);
            }
            if (__all(ok)) break;            // common path: first pass
            if (++g2 > GUARD) break;         // anti-hang
            __builtin_amdgcn_s_sleep(1);     // straggler: let stores land
        }

        // ---- 3. gates ----
        #pragma unroll
        for (int i = 0; i < 4; ++i) {
            float xr = bf2f(gr_.s[i]) + ar[i] + sbr[i];
            float xz = bf2f(gz_.s[i]) + az[i] + sbz[i];
            float r  = __builtin_amdgcn_rcpf(1.f + __expf(-xr));
            float z  = __builtin_amdgcn_rcpf(1.f + __expf(-xz));
            float xn = bf2f(gn_.s[i]) + sbn_i[i] + r * (an[i] + sbn_h[i]);
            float e2 = __expf(2.f * xn);
            float n  = 1.f - 2.f * __builtin_amdgcn_rcpf(1.f + e2);   // tanh
            float hnv = (1.f - z) * n + z * hp[i];
            hnv = pv * hp[i] + (1.f - pv) * hnv;
            hp[i] = hnv;
        }

        int rowg = t * 32 + b;

        // ---- 4. publish: 2 tagged u64 stores + flag. NO waitcnt ACK. ----
        if (t < 511) {
            unsigned long long tg1 = (unsigned long long)(t + 1);
            unsigned p01 = ((unsigned)(unsigned short)f2bf(hp[1]) << 16)
                         |  (unsigned)(unsigned short)f2bf(hp[0]);
            unsigned p23 = ((unsigned)(unsigned short)f2bf(hp[3]) << 16)
                         |  (unsigned)(unsigned short)f2bf(hp[2]);
            unsigned long long* hwr =
                hb3 + (size_t)((((t + 1) & 1) * 32 + b)) * 512 + (jq >> 1);
            __hip_atomic_store(hwr,     ((unsigned long long)p01 << 32) | tg1,
                               __ATOMIC_RELAXED, __HIP_MEMORY_SCOPE_AGENT);
            __hip_atomic_store(hwr + 1, ((unsigned long long)p23 << 32) | tg1,
                               __ATOMIC_RELAXED, __HIP_MEMORY_SCOPE_AGENT);
            if (l == 0)
                __hip_atomic_store(flags + bid * 2 + w, (unsigned)(t + 1),
                                   __ATOMIC_RELAXED, __HIP_MEMORY_SCOPE_AGENT);
        }

        // ---- 5. out stores + gi/pad prefetch, strictly after publish ----
        float4 o4 = { hp[0], hp[1], hp[2], hp[3] };
        *reinterpret_cast<float4*>(out + (size_t)rowg * 1024 + jq) = o4;
        if (t == 511) {
            *reinterpret_cast<float4*>(out + 16777216 + b * 1024 + jq) = o4;
            *reinterpret_cast<float4*>(out + 16809984 + b * 1024 + jq) = o4;
        }

        if (t < 511) {
            const short* gp = gi + (size_t)((t + 1) * 32 + b) * 3072 + jq;
            gr_.u = *reinterpret_cast<const unsigned long long*>(gp);
            gz_.u = *reinterpret_cast<const unsigned long long*>(gp + 1024);
            gn_.u = *reinterpret_cast<const unsigned long long*>(gp + 2048);
            pv = pad[(t + 1) * 32 + b];
        }
    }
}

// ---------------------------------------------------------------------------
extern "C" void kernel_launch(void* const* d_in, const int* in_sizes, int n_in,
                              void* d_out, int out_size, void* d_ws, size_t ws_size,
                              hipStream_t stream) {
    const float* X   = (const float*)d_in[0];
    const float* pad = (const float*)d_in[1];
    const float* Wih = (const float*)d_in[2];
    const float* Whh = (const float*)d_in[3];
    const float* bih = (const float*)d_in[4];
    const float* bhh = (const float*)d_in[5];
    float* out = (float*)d_out;

    char* ws = (char*)d_ws;
    short*    gi    = (short*)(ws);                      // 100,663,296 B
    short*    Wih_t = (short*)(ws + 100663296);          //   6,291,456 B (dead after gemm)
    short*    Whh_t = (short*)(ws + 106954752);          //   6,291,456 B
    unsigned long long* hb3 =
        (unsigned long long*)(ws + 100663296);           // reuses Wih_t: 262,144 B
    unsigned* flags = (unsigned*)(ws + 100663296 + 262144);  // 512 B

    hipLaunchKernelGGL(k_transpose_bf16, dim3(1536), dim3(256), 0, stream, Wih, Wih_t);
    hipLaunchKernelGGL(k_transpose_bf16, dim3(1536), dim3(256), 0, stream, Whh, Whh_t);
    hipLaunchKernelGGL(k_gemm_gi, dim3(256 * 48), dim3(256), 0, stream, X, Wih_t, gi);

    // Zero the tagged-u64 buffer (h0 = 0, tags = 0 = valid step-0 state)
    // + flags. Enqueued AFTER the gemm so the Wih_t aliasing is stream-safe.
    hipMemsetAsync(hb3, 0, 262144 + 512, stream);

    hipFuncSetAttribute((const void*)k_gru,
                        hipFuncAttributeMaxDynamicSharedMemorySize, 99072);
    hipLaunchKernelGGL(k_gru, dim3(NB), dim3(128), 99072, stream,
                       pad, gi, Whh_t, bih, bhh, hb3, flags, out);
}

// Round 8
// 2562.123 us; speedup vs baseline: 3.4620x; 1.9194x over previous
//
#include <hip/hip_runtime.h>
#include <cmath>

// T=512, B=32, D=1024, H=1024, 3H=3072
// d_out: outputs (512*32*1024) ++ outputs[-1] (32*1024) ++ h_last (32*1024)  fp32

typedef short s8v  __attribute__((ext_vector_type(8)));   // 8 x bf16 (raw bits)
typedef float f4v  __attribute__((ext_vector_type(4)));   // MFMA accumulator

#define NB 64       // blocks in the GRU grid
#define GUARD 16384 // bounded-spin: degrade to wrong-answer instead of hanging

__device__ __forceinline__ short f2bf(float f) {
    return __builtin_bit_cast(short, (__bf16)f);          // RNE convert
}
__device__ __forceinline__ float bf2f(short s) {
    return (float)__builtin_bit_cast(__bf16, s);
}

// ---------------------------------------------------------------------------
// Transpose W [1024][3072] fp32  ->  Wt [3072][1024] bf16.
// ---------------------------------------------------------------------------
__global__ __launch_bounds__(256) void k_transpose_bf16(
        const float* __restrict__ W, short* __restrict__ Wt) {
    __shared__ short Ls[32][72];
    int bk = blockIdx.x & 31;
    int bn = blockIdx.x >> 5;
    int k0 = bk * 32, n0 = bn * 64;
    int tid = threadIdx.x;
    {
        int r  = tid >> 3;
        int c0 = (tid & 7) * 8;
        const float* src = W + (size_t)(k0 + r) * 3072 + n0 + c0;
        float4 f0 = *reinterpret_cast<const float4*>(src);
        float4 f1 = *reinterpret_cast<const float4*>(src + 4);
        Ls[r][c0+0] = f2bf(f0.x); Ls[r][c0+1] = f2bf(f0.y);
        Ls[r][c0+2] = f2bf(f0.z); Ls[r][c0+3] = f2bf(f0.w);
        Ls[r][c0+4] = f2bf(f1.x); Ls[r][c0+5] = f2bf(f1.y);
        Ls[r][c0+6] = f2bf(f1.z); Ls[r][c0+7] = f2bf(f1.w);
    }
    __syncthreads();
    {
        int j   = tid >> 2;
        int kk0 = (tid & 3) * 8;
        s8v v;
        #pragma unroll
        for (int s = 0; s < 8; ++s) v[s] = Ls[kk0 + s][j];
        *reinterpret_cast<s8v*>(Wt + (size_t)(n0 + j) * 1024 + k0 + kk0) = v;
    }
}

// ---------------------------------------------------------------------------
// gi = X @ W_ih.  M=16384, N=3072, K=1024.  Output bf16.
// ---------------------------------------------------------------------------
__global__ __launch_bounds__(256) void k_gemm_gi(
        const float* __restrict__ X, const short* __restrict__ Wt,
        short* __restrict__ gi) {
    __shared__ short As[64][40];
    __shared__ short Bs[64][40];
    int bm = blockIdx.x & 255;
    int bn = blockIdx.x >> 8;
    int m0 = bm * 64, n0 = bn * 64;
    int tid = threadIdx.x;
    int wid = tid >> 6, l = tid & 63;
    int wm = wid >> 1, wn = wid & 1;
    int lr = l & 15, q = l >> 4;
    f4v acc[2][2] = {};
    int sr = tid >> 2;
    int sc = (tid & 3) * 8;

    for (int kc = 0; kc < 1024; kc += 32) {
        const float* asrc = X + (size_t)(m0 + sr) * 1024 + kc + sc;
        float4 f0 = *reinterpret_cast<const float4*>(asrc);
        float4 f1 = *reinterpret_cast<const float4*>(asrc + 4);
        s8v av;
        av[0]=f2bf(f0.x); av[1]=f2bf(f0.y); av[2]=f2bf(f0.z); av[3]=f2bf(f0.w);
        av[4]=f2bf(f1.x); av[5]=f2bf(f1.y); av[6]=f2bf(f1.z); av[7]=f2bf(f1.w);
        *reinterpret_cast<s8v*>(&As[sr][sc]) = av;
        *reinterpret_cast<s8v*>(&Bs[sr][sc]) =
            *reinterpret_cast<const s8v*>(Wt + (size_t)(n0 + sr) * 1024 + kc + sc);
        __syncthreads();
        s8v a0 = *reinterpret_cast<const s8v*>(&As[wm*32 +  0 + lr][q*8]);
        s8v a1 = *reinterpret_cast<const s8v*>(&As[wm*32 + 16 + lr][q*8]);
        s8v b0 = *reinterpret_cast<const s8v*>(&Bs[wn*32 +  0 + lr][q*8]);
        s8v b1 = *reinterpret_cast<const s8v*>(&Bs[wn*32 + 16 + lr][q*8]);
        acc[0][0] = __builtin_amdgcn_mfma_f32_16x16x32_bf16(a0, b0, acc[0][0], 0,0,0);
        acc[0][1] = __builtin_amdgcn_mfma_f32_16x16x32_bf16(a0, b1, acc[0][1], 0,0,0);
        acc[1][0] = __builtin_amdgcn_mfma_f32_16x16x32_bf16(a1, b0, acc[1][0], 0,0,0);
        acc[1][1] = __builtin_amdgcn_mfma_f32_16x16x32_bf16(a1, b1, acc[1][1], 0,0,0);
        __syncthreads();
    }
    #pragma unroll
    for (int ms = 0; ms < 2; ++ms)
      #pragma unroll
      for (int ns = 0; ns < 2; ++ns) {
        int m = m0 + wm*32 + ms*16 + q*4;
        int n = n0 + wn*32 + ns*16 + lr;
        #pragma unroll
        for (int i = 0; i < 4; ++i)
            gi[(size_t)(m + i) * 3072 + n] = f2bf(acc[ms][ns][i]);
      }
}

// ---------------------------------------------------------------------------
// GRU recurrence v11 — round-0's proven ACK protocol + 3 measured fixes.
//
// Protocol = round-0 exactly: untagged u64 h quanta (4 x bf16, 64-bit
// naturally aligned => single-copy atomic), producer publishes h-chunk ->
// s_waitcnt(0) ACK -> raises its flag; consumer waits flags >= t before
// reading (the wait doubles as the overwrite-safety gate: all own-half
// flags >= t  <=>  every own-half wave consumed t-1).
//
// Fixes (each independently safe, from v6-v10 counter evidence):
//  1. gi/pad HBM prefetch moved AFTER the flag store — round-0's ACK
//     waitcnt(0) drained the prefetch (~1us HBM) on the publish path.
//     Prefetch latency now hides under the next flag-wait + burst.
//  2. Own-half flag wait only (halves own disjoint batch rows; round-0
//     waited on both halves = pure tail latency).
//  3. Coalesced h layout [parity][half][k][slot] (slot = consumer lane):
//     consumer burst instr k reads ONE contiguous 512B run (vs 16
//     half-used lines); producer store = 4 x 128B runs (vs 16 x 32B).
//     Bijection: u64 of (row b, col-group m=col/4) lives at
//     k = 2*(m>>3)|(m&1), slot = ((m&7)>>1)*16 + (b&15); consumer's
//     hreg[k] then equals round-0's hreg[2it+jj] -> MFMA unpack unchanged.
// hb4: [2][2][64][64] u64 = 128KiB; memset(0) = valid h0. flags [2][64].
// ---------------------------------------------------------------------------
__global__ __launch_bounds__(128, 1) void k_gru(
        const float* __restrict__ pad,   // [512][32]
        const short* __restrict__ gi,    // [16384][3072] bf16 (no bias)
        const short* __restrict__ Whht,  // [3072][1024] bf16
        const float* __restrict__ b_ih,  // [3072]
        const float* __restrict__ b_hh,  // [3072]
        unsigned long long* __restrict__ hb4,  // [2][2][64][64] u64 (zeroed)
        unsigned* __restrict__ flags,    // [2][64] step flags (pre-zeroed)
        float* __restrict__ out) {
    extern __shared__ short wlds[];      // 48 rows x 1024, stride 1032 shorts
    const int WS = 1032;
    int bid = blockIdx.x;                // 0..63
    int j0  = bid * 16;
    int tid = threadIdx.x;               // 0..127
    int w   = tid >> 6;                  // batch half
    int l   = tid & 63, lr = l & 15, q = l >> 4;

    // Stage weight slice: rows (gate g, col c) x 1024 shorts. (both waves)
    for (int idx = tid; idx < 48 * 128; idx += 128) {
        int row = idx >> 7;
        int ko  = (idx & 127) * 8;
        int g = row >> 4, c = row & 15;
        *reinterpret_cast<s8v*>(&wlds[(g * 16 + c) * WS + ko]) =
            *reinterpret_cast<const s8v*>(Whht + (size_t)(g * 1024 + j0 + c) * 1024 + ko);
    }
    __syncthreads();                     // weights ready; last sync in kernel

    int jq = j0 + q * 4;                 // first of this lane's 4 j-cols
    int b  = w * 16 + lr;                // this lane's batch row
    f4v sbr = *reinterpret_cast<const f4v*>(b_ih + jq)
            + *reinterpret_cast<const f4v*>(b_hh + jq);
    f4v sbz = *reinterpret_cast<const f4v*>(b_ih + 1024 + jq)
            + *reinterpret_cast<const f4v*>(b_hh + 1024 + jq);
    f4v sbn_i = *reinterpret_cast<const f4v*>(b_ih + 2048 + jq);
    f4v sbn_h = *reinterpret_cast<const f4v*>(b_hh + 2048 + jq);
    const short* w_r = &wlds[(0 * 16 + lr) * WS + q * 8];
    const short* w_z = &wlds[(1 * 16 + lr) * WS + q * 8];
    const short* w_n = &wlds[(2 * 16 + lr) * WS + q * 8];
    float hp[4] = {0.f, 0.f, 0.f, 0.f};

    const unsigned* myflag = flags + w * 64 + l;   // own-half flag of block l

    // Publish slot (loop-invariant except parity): col-group m = bid*4+q.
    int m_  = bid * 4 + q;
    int kk_ = ((m_ >> 3) << 1) | (m_ & 1);
    int sl_ = ((m_ & 7) >> 1) * 16 + lr;
    unsigned long long* hw0 = hb4 + (size_t)w * 4096 + kk_ * 64 + sl_;       // parity 0
    unsigned long long* hw1 = hw0 + 8192;                                    // parity 1
    // Consume base (parity 0/1): instruction k reads base[k*64], lane-offset l.
    const unsigned long long* hc0 = hb4 + (size_t)w * 4096 + l;
    const unsigned long long* hc1 = hc0 + 8192;

    union u64s { unsigned long long u; short s[4]; };
    u64s gr_, gz_, gn_; float pv;
    {   // prefetch gi/pad for t=0
        const short* gp = gi + (size_t)b * 3072 + jq;
        gr_.u = *reinterpret_cast<const unsigned long long*>(gp);
        gz_.u = *reinterpret_cast<const unsigned long long*>(gp + 1024);
        gn_.u = *reinterpret_cast<const unsigned long long*>(gp + 2048);
        pv = pad[b];
    }

    for (int t = 0; t < 512; ++t) {
        // ---- 1. flag wait (own half only): detect + overwrite-safety ----
        if (t) {
            unsigned uT = (unsigned)t;
            int g1 = 0;
            for (;;) {
                unsigned f = __hip_atomic_load(myflag, __ATOMIC_RELAXED,
                                               __HIP_MEMORY_SCOPE_AGENT);
                if (__all((int)(f >= uT))) break;
                if (++g1 > GUARD) break;     // anti-hang: degrade, don't die
                __builtin_amdgcn_s_sleep(1);
            }
        }

        // ---- 2. burst: 64 u64 loads, each instr = contiguous 512B ----
        const unsigned long long* hbase = (t & 1) ? hc1 : hc0;
        unsigned long long hreg[64];
        #pragma unroll
        for (int k = 0; k < 64; ++k)
            hreg[k] = __hip_atomic_load(hbase + (size_t)k * 64,
                                        __ATOMIC_RELAXED, __HIP_MEMORY_SCOPE_AGENT);

        // ---- 3. MFMA consume (identical to round-0) ----
        f4v ar = {0,0,0,0}, az = {0,0,0,0}, an = {0,0,0,0};
        #pragma unroll
        for (int it = 0; it < 32; ++it) {
            union { unsigned long long u[2]; s8v v; } hx;
            hx.u[0] = hreg[2*it]; hx.u[1] = hreg[2*it+1];
            s8v r8 = *reinterpret_cast<const s8v*>(w_r + it * 32);
            s8v z8 = *reinterpret_cast<const s8v*>(w_z + it * 32);
            s8v n8 = *reinterpret_cast<const s8v*>(w_n + it * 32);
            ar = __builtin_amdgcn_mfma_f32_16x16x32_bf16(r8, hx.v, ar, 0,0,0);
            az = __builtin_amdgcn_mfma_f32_16x16x32_bf16(z8, hx.v, az, 0,0,0);
            an = __builtin_amdgcn_mfma_f32_16x16x32_bf16(n8, hx.v, an, 0,0,0);
        }

        // ---- 4. gates ----
        #pragma unroll
        for (int i = 0; i < 4; ++i) {
            float xr = bf2f(gr_.s[i]) + ar[i] + sbr[i];
            float xz = bf2f(gz_.s[i]) + az[i] + sbz[i];
            float r  = __builtin_amdgcn_rcpf(1.f + __expf(-xr));
            float z  = __builtin_amdgcn_rcpf(1.f + __expf(-xz));
            float xn = bf2f(gn_.s[i]) + sbn_i[i] + r * (an[i] + sbn_h[i]);
            float e2 = __expf(2.f * xn);
            float n  = 1.f - 2.f * __builtin_amdgcn_rcpf(1.f + e2);   // tanh
            float hnv = (1.f - z) * n + z * hp[i];
            hnv = pv * hp[i] + (1.f - pv) * hnv;
            hp[i] = hnv;
        }

        int rowg = t * 32 + b;

        // ---- 5. publish: h store -> ACK -> flag. (prefetch NOT in flight,
        //         so the waitcnt drains ~one L3 store RT only) ----
        if (t < 511) {
            u64s pk;
            pk.s[0] = f2bf(hp[0]); pk.s[1] = f2bf(hp[1]);
            pk.s[2] = f2bf(hp[2]); pk.s[3] = f2bf(hp[3]);
            unsigned long long* hwr = ((t + 1) & 1) ? hw1 : hw0;
            __hip_atomic_store(hwr, pk.u, __ATOMIC_RELAXED, __HIP_MEMORY_SCOPE_AGENT);
            __builtin_amdgcn_s_waitcnt(0);       // h store visible at L3
            if (l == 0)
                __hip_atomic_store(flags + w * 64 + bid, (unsigned)(t + 1),
                                   __ATOMIC_RELAXED, __HIP_MEMORY_SCOPE_AGENT);
        }

        // ---- 6. out stores after the flag — drain overlaps next spin ----
        float4 o4 = { hp[0], hp[1], hp[2], hp[3] };
        *reinterpret_cast<float4*>(out + (size_t)rowg * 1024 + jq) = o4;
        if (t == 511) {
            *reinterpret_cast<float4*>(out + 16777216 + b * 1024 + jq) = o4;
            *reinterpret_cast<float4*>(out + 16809984 + b * 1024 + jq) = o4;
        }

        // ---- 7. gi/pad prefetch for t+1, AFTER publish (off ACK path);
        //         its HBM latency hides under the next flag-wait + burst ----
        if (t < 511) {
            const short* gp = gi + (size_t)((t + 1) * 32 + b) * 3072 + jq;
            gr_.u = *reinterpret_cast<const unsigned long long*>(gp);
            gz_.u = *reinterpret_cast<const unsigned long long*>(gp + 1024);
            gn_.u = *reinterpret_cast<const unsigned long long*>(gp + 2048);
            pv = pad[(t + 1) * 32 + b];
        }
    }
}

// ---------------------------------------------------------------------------
extern "C" void kernel_launch(void* const* d_in, const int* in_sizes, int n_in,
                              void* d_out, int out_size, void* d_ws, size_t ws_size,
                              hipStream_t stream) {
    const float* X   = (const float*)d_in[0];
    const float* pad = (const float*)d_in[1];
    const float* Wih = (const float*)d_in[2];
    const float* Whh = (const float*)d_in[3];
    const float* bih = (const float*)d_in[4];
    const float* bhh = (const float*)d_in[5];
    float* out = (float*)d_out;

    char* ws = (char*)d_ws;
    short*    gi    = (short*)(ws);                      // 100,663,296 B
    short*    Wih_t = (short*)(ws + 100663296);          //   6,291,456 B (dead after gemm)
    short*    Whh_t = (short*)(ws + 106954752);          //   6,291,456 B
    unsigned long long* hb4 =
        (unsigned long long*)(ws + 100663296);           // reuses Wih_t: 131,072 B
    unsigned* flags = (unsigned*)(ws + 100663296 + 131072);  // 512 B

    hipLaunchKernelGGL(k_transpose_bf16, dim3(1536), dim3(256), 0, stream, Wih, Wih_t);
    hipLaunchKernelGGL(k_transpose_bf16, dim3(1536), dim3(256), 0, stream, Whh, Whh_t);
    hipLaunchKernelGGL(k_gemm_gi, dim3(256 * 48), dim3(256), 0, stream, X, Wih_t, gi);

    // Zero the h buffer (h0 = 0) + flags. Enqueued AFTER the gemm so the
    // Wih_t aliasing is stream-safe.
    hipMemsetAsync(hb4, 0, 131072 + 512, stream);

    hipFuncSetAttribute((const void*)k_gru,
                        hipFuncAttributeMaxDynamicSharedMemorySize, 99072);
    hipLaunchKernelGGL(k_gru, dim3(NB), dim3(128), 99072, stream,
                       pad, gi, Whh_t, bih, bhh, hb4, flags, out);
}